// Round 2
// baseline (13211.931 us; speedup 1.0000x reference)
//
#include <hip/hip_runtime.h>

typedef unsigned short u16;
typedef __attribute__((ext_vector_type(8))) short bf16x8;   // 8 x bf16 (4 VGPRs)
typedef __attribute__((ext_vector_type(4))) float f32x4;

#define MFMA16(a, b, c) __builtin_amdgcn_mfma_f32_16x16x32_bf16((a), (b), (c), 0, 0, 0)

__device__ __forceinline__ u16 f2bf(float f) {
  union { float f; unsigned u; } v; v.f = f;
  unsigned r = v.u + 0x7FFF + ((v.u >> 16) & 1);   // round-to-nearest-even
  return (u16)(r >> 16);
}
__device__ __forceinline__ float bf2f(u16 h) {
  union { unsigned u; float f; } v; v.u = ((unsigned)h) << 16;
  return v.f;
}

// ---------- f32 -> bf16 bulk convert (n multiple of 8) ----------
__global__ void k_convert(const float* __restrict__ src, u16* __restrict__ dst, int n8) {
  int i = blockIdx.x * 256 + threadIdx.x;
  if (i >= n8) return;
  const float4* s = (const float4*)src + (size_t)i * 2;
  float4 a = s[0], b = s[1];
  u16 o[8] = { f2bf(a.x), f2bf(a.y), f2bf(a.z), f2bf(a.w),
               f2bf(b.x), f2bf(b.y), f2bf(b.z), f2bf(b.w) };
  *(bf16x8*)(dst + (size_t)i * 8) = *(bf16x8*)o;
}

// ---------- embedding gather -> A0 bf16, row i = t*64 + b ----------
__global__ void k_gather(const int* __restrict__ x, const float* __restrict__ emb,
                         u16* __restrict__ A0) {
  int gid = blockIdx.x * 256 + threadIdx.x;   // 32768 rows * 128 thr/row
  int row = gid >> 7;
  int e = (gid & 127) << 3;
  int t = row >> 6, b = row & 63;
  int v = x[b * 512 + t];
  const float4* s = (const float4*)(emb + (size_t)v * 1024 + e);
  float4 a = s[0], c = s[1];
  u16 o[8] = { f2bf(a.x), f2bf(a.y), f2bf(a.z), f2bf(a.w),
               f2bf(c.x), f2bf(c.y), f2bf(c.z), f2bf(c.w) };
  *(bf16x8*)(A0 + (size_t)row * 1024 + e) = *(bf16x8*)o;
}

// ---------- h0 init: f32 copy + bf16 copy (65536 elems) ----------
__global__ void k_hinit(const float* __restrict__ h0l, float* __restrict__ hf,
                        u16* __restrict__ hbf) {
  int i = blockIdx.x * 256 + threadIdx.x;
  float v = h0l[i];
  hf[i] = v;
  hbf[i] = f2bf(v);
}

// ---------- big GEMM: C[M=32768][3072] = A[M][1024] @ W[3072][1024]^T + bias ----------
// 128x128 tile, 4 waves (2x2), each wave 64x64 = 4x4 frags of 16x16x32.
__global__ __launch_bounds__(256) void k_gemm(const u16* __restrict__ A,
                                              const u16* __restrict__ W,
                                              const float* __restrict__ bias,
                                              u16* __restrict__ C) {
  __shared__ __attribute__((aligned(16))) u16 As[128 * 40];
  __shared__ __attribute__((aligned(16))) u16 Bs[128 * 40];
  int tid = threadIdx.x;
  int m0 = blockIdx.x * 128;
  int n0 = blockIdx.y * 128;
  int lane = tid & 63, wave = tid >> 6;
  int quad = lane >> 4, l15 = lane & 15;
  int wm = (wave >> 1) * 64, wn = (wave & 1) * 64;
  f32x4 acc[4][4] = {};
  for (int kc = 0; kc < 1024; kc += 32) {
#pragma unroll
    for (int i = 0; i < 2; i++) {
      int g = tid + i * 256;            // 0..511: row = g/4, kg = (g%4)*8
      int row = g >> 2, kg = (g & 3) << 3;
      *(bf16x8*)(As + row * 40 + kg) = *(const bf16x8*)(A + (size_t)(m0 + row) * 1024 + kc + kg);
      *(bf16x8*)(Bs + row * 40 + kg) = *(const bf16x8*)(W + (size_t)(n0 + row) * 1024 + kc + kg);
    }
    __syncthreads();
    bf16x8 af[4], bf[4];
#pragma unroll
    for (int mi = 0; mi < 4; mi++)
      af[mi] = *(const bf16x8*)(As + (wm + mi * 16 + l15) * 40 + quad * 8);
#pragma unroll
    for (int ni = 0; ni < 4; ni++)
      bf[ni] = *(const bf16x8*)(Bs + (wn + ni * 16 + l15) * 40 + quad * 8);
#pragma unroll
    for (int mi = 0; mi < 4; mi++)
#pragma unroll
      for (int ni = 0; ni < 4; ni++)
        acc[mi][ni] = MFMA16(af[mi], bf[ni], acc[mi][ni]);
    __syncthreads();
  }
  // C/D layout: n = lane&15 (+tile), m = quad*4 + reg (+tile)
#pragma unroll
  for (int mi = 0; mi < 4; mi++)
#pragma unroll
    for (int ni = 0; ni < 4; ni++)
#pragma unroll
      for (int r = 0; r < 4; r++) {
        int m = m0 + wm + mi * 16 + quad * 4 + r;
        int n = n0 + wn + ni * 16 + l15;
        C[(size_t)m * 3072 + n] = f2bf(acc[mi][ni][r] + bias[n]);
      }
}

// ---------- GRU step: gh = h @ Whh^T (+bhh), gates, hnew ----------
// 128 blocks x 128 threads. Block (j-group = bid/2, m-half = bid&1); each wave = 1 M-tile.
// Block stages Whh rows {j0..j0+15} for gates r,z,n (48 rows) in K-chunks of 128.
__global__ __launch_bounds__(128) void k_step(
    const u16* __restrict__ hbf_in, const float* __restrict__ hf_in,
    const u16* __restrict__ Whh, const float* __restrict__ bhh,
    const u16* __restrict__ gx_t,
    u16* __restrict__ hbf_out, float* __restrict__ hf_out,
    float* __restrict__ hiddens_out,   // pre-offset by t*1024; stride 524288 per b; or null
    float* __restrict__ hfin1, float* __restrict__ hfin2) {
  __shared__ __attribute__((aligned(16))) u16 Bs[48 * 136];
  int tid = threadIdx.x;
  int lane = tid & 63, wave = tid >> 6;     // wave: 0..1
  int quad = lane >> 4, l15 = lane & 15;
  int j0 = (blockIdx.x >> 1) * 16;
  int mtile = (blockIdx.x & 1) * 2 + wave;  // 0..3 -> batch rows mtile*16..+15
  f32x4 acc[3] = {};
  for (int kc = 0; kc < 1024; kc += 128) {
#pragma unroll
    for (int i = 0; i < 6; i++) {
      int g = tid + i * 128;                // 0..767: row = g/16, kg = (g%16)*8
      int row = g >> 4, kg = (g & 15) << 3;
      int gate = row >> 4, jr = row & 15;
      *(bf16x8*)(Bs + row * 136 + kg) =
          *(const bf16x8*)(Whh + (size_t)(gate * 1024 + j0 + jr) * 1024 + kc + kg);
    }
    __syncthreads();
#pragma unroll
    for (int kk = 0; kk < 128; kk += 32) {
      bf16x8 a = *(const bf16x8*)(hbf_in + (size_t)(mtile * 16 + l15) * 1024 + kc + kk + quad * 8);
#pragma unroll
      for (int g = 0; g < 3; g++) {
        bf16x8 b = *(const bf16x8*)(Bs + (g * 16 + l15) * 136 + kk + quad * 8);
        acc[g] = MFMA16(a, b, acc[g]);
      }
    }
    __syncthreads();
  }
  int j = j0 + l15;
  float br = bhh[j], bz = bhh[1024 + j], bn = bhh[2048 + j];
#pragma unroll
  for (int r = 0; r < 4; r++) {
    int m = mtile * 16 + quad * 4 + r;
    float xr = bf2f(gx_t[m * 3072 + j]);
    float xz = bf2f(gx_t[m * 3072 + 1024 + j]);
    float xn = bf2f(gx_t[m * 3072 + 2048 + j]);
    float rg = 1.f / (1.f + __expf(-(xr + acc[0][r] + br)));
    float zg = 1.f / (1.f + __expf(-(xz + acc[1][r] + bz)));
    float nx = xn + rg * (acc[2][r] + bn);
    nx = fminf(15.f, fmaxf(-15.f, nx));
    float e2 = __expf(2.f * nx);
    float ng = (e2 - 1.f) / (e2 + 1.f);
    float hold = hf_in[m * 1024 + j];
    float hnew = (1.f - zg) * ng + zg * hold;
    hf_out[m * 1024 + j] = hnew;
    hbf_out[m * 1024 + j] = f2bf(hnew);
    if (hiddens_out) hiddens_out[(size_t)m * 524288 + j] = hnew;
    if (hfin1) hfin1[m * 1024 + j] = hnew;
    if (hfin2) hfin2[m * 1024 + j] = hnew;
  }
}

extern "C" void kernel_launch(void* const* d_in, const int* in_sizes, int n_in,
                              void* d_out, int out_size, void* d_ws, size_t ws_size,
                              hipStream_t stream) {
  const int*   x   = (const int*)d_in[0];
  const float* h0  = (const float*)d_in[1];
  const float* emb = (const float*)d_in[2];
  const float* Wih = (const float*)d_in[3];
  const float* Whh = (const float*)d_in[4];
  const float* bih = (const float*)d_in[5];
  const float* bhh = (const float*)d_in[6];
  float* out = (float*)d_out;

  // workspace layout (total ~362 MB)
  char* ws = (char*)d_ws;
  u16* WihB = (u16*)ws;  ws += 12582912;            // [2][3072][1024] bf16
  u16* WhhB = (u16*)ws;  ws += 12582912;            // [2][3072][1024] bf16
  u16* A0   = (u16*)ws;  ws += 67108864;            // [32768][1024] bf16 (emb rows, t-major)
  u16* A1   = (u16*)ws;  ws += 67108864;            // [32768][1024] bf16 (layer-0 states)
  u16* gx   = (u16*)ws;  ws += 201326592;           // [32768][3072] bf16 (reused layer0/layer1)
  u16* h0bf = (u16*)ws;  ws += 262144;              // bf16 h0 (layer 0 region used)
  float* hfA = (float*)ws; ws += 262144;            // f32 h double-buffer
  float* hfB = (float*)ws; ws += 262144;
  u16* hbfA = (u16*)ws;  ws += 131072;              // layer-1 bf16 h double-buffer
  u16* hbfB = (u16*)ws;  ws += 131072;

  float* out_out = out;                 // [1,64,1024]
  float* hidden0 = out + 65536;         // [64,1024]
  float* hidden1 = out + 131072;        // [64,1024]
  float* hiddens = out + 196608;        // [64][512][1024]

  // per-layer stride for [L][3072][1024] weights = 3072*1024 elements
  const size_t WSTRIDE = 3145728;   // BUGFIX r1: was 6291456 (2x stride, OOB for layer 1)

  k_convert<<<3072, 256, 0, stream>>>(Wih, WihB, 786432);  // 6291456/8
  k_convert<<<3072, 256, 0, stream>>>(Whh, WhhB, 786432);
  k_gather<<<16384, 256, 0, stream>>>(x, emb, A0);
  k_hinit<<<256, 256, 0, stream>>>(h0, hfA, h0bf);

  dim3 ggrid(256, 24);
  k_gemm<<<ggrid, 256, 0, stream>>>(A0, WihB, bih, gx);

  for (int t = 0; t < 512; t++) {
    const u16* hb_in = (t == 0) ? h0bf : (A1 + (size_t)(t - 1) * 65536);
    const float* hf_in = (t & 1) ? hfB : hfA;
    float* hf_out = (t & 1) ? hfA : hfB;
    k_step<<<128, 128, 0, stream>>>(hb_in, hf_in, WhhB, bhh,
        gx + (size_t)t * 196608, A1 + (size_t)t * 65536, hf_out,
        hiddens + (size_t)t * 1024, (t == 511) ? hidden0 : nullptr, nullptr);
  }

  k_hinit<<<256, 256, 0, stream>>>(h0 + 65536, hfA, hbfA);
  k_gemm<<<ggrid, 256, 0, stream>>>(A1, WihB + WSTRIDE, bih + 3072, gx);

  for (int t = 0; t < 512; t++) {
    const u16* hb_in = (t & 1) ? hbfB : hbfA;
    u16* hb_out = (t & 1) ? hbfA : hbfB;
    const float* hf_in = (t & 1) ? hfB : hfA;
    float* hf_out = (t & 1) ? hfA : hfB;
    k_step<<<128, 128, 0, stream>>>(hb_in, hf_in, WhhB + WSTRIDE, bhh + 3072,
        gx + (size_t)t * 196608, hb_out, hf_out,
        nullptr, (t == 511) ? hidden1 : nullptr, (t == 511) ? out_out : nullptr);
  }
}